// Round 3
// baseline (520.349 us; speedup 1.0000x reference)
//
#include <hip/hip_runtime.h>
#include <cstdint>

#define G   8      // batches per block
#define KT  2048   // C*D = 64*32

// W4 layout: W4[e4][k][dd] (e = e4*4+dd, k in [0,32)): W4[e4*128 + k*4 + dd] = W[j][k][m], e = j*32+m
__global__ __launch_bounds__(1024) void wtrans_kernel(const float* __restrict__ W,
                                                      float* __restrict__ W4) {
    int j = blockIdx.x;           // [0,64)
    int t = threadIdx.x;          // k*32 + m
    int k = t >> 5, m = t & 31;
    int e = j * 32 + m;
    W4[(e >> 2) * 128 + k * 4 + (e & 3)] = W[j * 1024 + t];
}

template <int CTRL>
__device__ __forceinline__ float dpp_shr_add(float v) {
    int moved = __builtin_amdgcn_update_dpp(0, __float_as_int(v), CTRL, 0xF, 0xF, true);
    return v + __int_as_float(moved);
}

// 512 threads = 8 waves; wave w owns k-quad [4w, 4w+4); G=8 batches per block.
// Phase 1 streams x global->VGPR (no LDS staging, no stage barrier).
// LDS: P[64*33] partials + S[256]  (~8.7 KB -> occupancy is VGPR-bound)
__global__ __launch_bounds__(512, 4) void ipf_kernel(const float* __restrict__ x,
                                                     const float* __restrict__ W4,
                                                     float* __restrict__ out) {
    __shared__ float Pp[64 * 33];
    __shared__ float Sl[256];
    const int t = threadIdx.x;
    const int w = t >> 6;             // wave id = k-quad owner, also phase-2 batch
    const int l = t & 63;             // lane = e4 slice owner, also phase-2 channel
    const long long b0 = (long long)blockIdx.x * G;
    const float* __restrict__ xb = x + b0 * KT;

    // ---- phase 1: acc[bb][q] = sum_e x[bb][e] * W[e][w*4+q], lane covers e4 = j*64+l ----
    float acc[G][4];
    #pragma unroll
    for (int bb = 0; bb < G; ++bb) {
        acc[bb][0] = 0.0f; acc[bb][1] = 0.0f; acc[bb][2] = 0.0f; acc[bb][3] = 0.0f;
    }

    #pragma unroll
    for (int j = 0; j < 8; ++j) {
        const int e4 = j * 64 + l;
        float4 wv[4];
        const float4* wp = (const float4*)(W4 + e4 * 128 + w * 16);
        #pragma unroll
        for (int q = 0; q < 4; ++q) wv[q] = wp[q];         // 64B contiguous per lane, L2-hot

        #pragma unroll
        for (int bb = 0; bb < G; ++bb) {
            const float4 xv = *(const float4*)(xb + bb * KT + e4 * 4);  // coalesced 1KB/wave
            #pragma unroll
            for (int q = 0; q < 4; ++q) {
                acc[bb][q] += xv.x * wv[q].x;
                acc[bb][q] += xv.y * wv[q].y;
                acc[bb][q] += xv.z * wv[q].z;
                acc[bb][q] += xv.w * wv[q].w;
            }
        }
    }

    // ---- intra-wave 8-lane DPP reduction (VALU pipe) ----
    #pragma unroll
    for (int bb = 0; bb < G; ++bb)
        #pragma unroll
        for (int q = 0; q < 4; ++q) {
            float v = acc[bb][q];
            v = dpp_shr_add<0x111>(v);   // row_shr:1
            v = dpp_shr_add<0x112>(v);   // row_shr:2
            v = dpp_shr_add<0x114>(v);   // row_shr:4 -> lane (l&7)==7 holds 8-lane sum
            acc[bb][q] = v;
        }

    if ((l & 7) == 7) {
        const int g = l >> 3;
        float* row = Pp + (w * 8 + g) * 33;   // stride-33 rows: bank-spread
        #pragma unroll
        for (int bb = 0; bb < G; ++bb)
            #pragma unroll
            for (int q = 0; q < 4; ++q)
                row[bb * 4 + q] = acc[bb][q];
    }
    __syncthreads();

    // ---- gather: S[bb][k] = sum_g P[(k/4)*8+g][bb*4 + k%4]  (first 4 waves) ----
    if (t < 256) {
        const int bb = t >> 5, k = t & 31;
        const int wq = k >> 2, kk = k & 3;
        float s = 0.0f;
        #pragma unroll
        for (int g = 0; g < 8; ++g)
            s += Pp[(wq * 8 + g) * 33 + bb * 4 + kk];
        Sl[bb * 32 + k] = s;
    }
    __syncthreads();

    // ---- phase 2: out[b0+w, l] = tanh(sum_d x[w][l*32+d] * S[w][d]) ----
    // x re-read from global: 128B/lane contiguous, block-hot in L1/L2/L3.
    {
        const float* xr = xb + w * KT + l * 32;
        const float* sr = Sl + w * 32;        // uniform per wave -> LDS broadcast reads
        float s = 0.0f;
        #pragma unroll
        for (int q = 0; q < 8; ++q) {
            const float4 xv = *(const float4*)(xr + q * 4);
            const float4 sv = *(const float4*)(sr + q * 4);
            s += xv.x * sv.x + xv.y * sv.y + xv.z * sv.z + xv.w * sv.w;
        }
        const float e2 = __expf(2.0f * s);    // tanh(s) = 1 - 2/(e^{2s}+1)
        out[(b0 + w) * 64 + l] = 1.0f - 2.0f / (e2 + 1.0f);
    }
}

extern "C" void kernel_launch(void* const* d_in, const int* in_sizes, int n_in,
                              void* d_out, int out_size, void* d_ws, size_t ws_size,
                              hipStream_t stream) {
    const float* x = (const float*)d_in[0];   // [65536,64,32] fp32
    const float* W = (const float*)d_in[1];   // [64,32,32] fp32
    float* out = (float*)d_out;               // [65536,64] fp32
    float* W4  = (float*)d_ws;                // 512*128 floats = 256 KB scratch

    wtrans_kernel<<<64, 1024, 0, stream>>>(W, W4);
    ipf_kernel<<<65536 / G, 512, 0, stream>>>(x, W4, out);
}